// Round 13
// baseline (699.119 us; speedup 1.0000x reference)
//
#include <hip/hip_runtime.h>
#include <hip/hip_bf16.h>
#include <cmath>

// SDYUnit: per-pixel conv chain via 32x32x16 fp16 MFMA. R13 = R12 with the
// staging bug fixed (frag = 64 uint4v, not 32: wl16 needs 384 writes and the
// mid-frag source starts at uint4v 384). 512-thread WGs share one 32KB LDS
// weight copy -> occupancy cap 32 waves/CU. Single fp16 weights + fp16
// activations: 76 MFMA/wave. Weight k-columns pre-permuted so packed
// accumulators ARE the next layer's B operand:
//   B-slot (h,j) of K-step ks <-> k' = (j&3) + 8*(2ks+(j>>2)) + 4h.

static constexpr int Hh = 190, Ww = 190, Him = 192, Wim = 192, Nimg = 24;
static constexpr int NPIX = Nimg * Hh * Ww;       // 866,400
static constexpr int NWG  = (NPIX + 511) / 512;   // 1693

typedef __attribute__((ext_vector_type(8)))  _Float16 half8v;  // 8 fp16 (4 VGPR)
typedef __attribute__((ext_vector_type(16))) float f32x16;     // C/D frag
typedef __attribute__((ext_vector_type(4)))  unsigned int uint4v;

// fragment indices in ws (each frag = 512 shorts = 1024 B = 64 uint4v)
static constexpr int FR_L1  = 0;    // +mt  (2 frags)
static constexpr int FR_L6  = 2;    // +ks  (4 frags)
static constexpr int FR_MID = 6;    // +(L*8 + mt*4 + ks)  (32 frags)
// compressed bias tables (floats; after 38 frags = 19456 shorts = 9728 f32)
static constexpr int BT_BASE = 9728;  // [0,256) mid [L][mt][b5][16]
                                      // [256,320) L1 [mt][b5][16]
                                      // [320,352) L6 [b5][16]

__global__ __launch_bounds__(256) void prep_kernel(
    const float* __restrict__ W1, const float* __restrict__ W2,
    const float* __restrict__ W3, const float* __restrict__ W4,
    const float* __restrict__ W5, const float* __restrict__ W6,
    const float* __restrict__ b1, const float* __restrict__ b2,
    const float* __restrict__ b3, const float* __restrict__ b4,
    const float* __restrict__ b5, const float* __restrict__ b6,
    short* __restrict__ ws) {
  float* wsF = (float*)ws;
  int t0 = blockIdx.x * 256 + threadIdx.x;
  int stride = gridDim.x * 256;
  // mid layers: A[row][k'], row = mt*32+(lane&31), k' per permuted slot map
  for (int idx = t0; idx < 32 * 512; idx += stride) {
    int j = idx & 7, lane = (idx >> 3) & 63, fi = idx >> 9;
    int ks = fi & 3, mt = (fi >> 2) & 1, L = fi >> 3;
    const float* W = (L == 0) ? W2 : (L == 1) ? W3 : (L == 2) ? W4 : W5;
    int g = mt * 32 + (lane & 31);
    int k = (j & 3) + 8 * (2 * ks + (j >> 2)) + 4 * (lane >> 5);
    _Float16 h = (_Float16)W[g * 64 + k];
    ws[(FR_MID + fi) * 512 + (idx & 511)] = __builtin_bit_cast(short, h);
  }
  // layer 1: taps in slots j=0..3 of BOTH halves (B zeroes the non-owner half)
  for (int idx = t0; idx < 2 * 512; idx += stride) {
    int j = idx & 7, lane = (idx >> 3) & 63, mt = idx >> 9;
    int g = mt * 32 + (lane & 31);
    float w = (j < 4) ? W1[g * 4 + j] : 0.f;
    _Float16 h = (_Float16)w;
    ws[(FR_L1 + mt) * 512 + (idx & 511)] = __builtin_bit_cast(short, h);
  }
  // layer 6: M=16 zero-padded to 32, same permuted k map
  for (int idx = t0; idx < 4 * 512; idx += stride) {
    int j = idx & 7, lane = (idx >> 3) & 63, ks = idx >> 9;
    int g = lane & 31;
    int k = (j & 3) + 8 * (2 * ks + (j >> 2)) + 4 * (lane >> 5);
    float w = (g < 16) ? W6[g * 64 + k] : 0.f;
    _Float16 h = (_Float16)w;
    ws[(FR_L6 + ks) * 512 + (idx & 511)] = __builtin_bit_cast(short, h);
  }
  // compressed bias tables: C/D reg r of lane-half b5 = row (r>>2)*8+b5*4+(r&3)
  for (int idx = t0; idx < 256; idx += stride) {   // mid [L][mt][b5][16]
    int r = idx & 15, b5v = (idx >> 4) & 1, mt = (idx >> 5) & 1, L = idx >> 6;
    const float* bb = (L == 0) ? b2 : (L == 1) ? b3 : (L == 2) ? b4 : b5;
    wsF[BT_BASE + idx] = bb[mt * 32 + (r >> 2) * 8 + b5v * 4 + (r & 3)];
  }
  for (int idx = t0; idx < 64; idx += stride) {    // L1 [mt][b5][16]
    int r = idx & 15, b5v = (idx >> 4) & 1, mt = idx >> 5;
    wsF[BT_BASE + 256 + idx] = b1[mt * 32 + (r >> 2) * 8 + b5v * 4 + (r & 3)];
  }
  for (int idx = t0; idx < 32; idx += stride) {    // L6 [b5][16] (rows>=8 zero)
    int r = idx & 15, b5v = idx >> 4;
    wsF[BT_BASE + 320 + idx] = (r < 8) ? b6[(r >> 2) * 8 + b5v * 4 + (r & 3)] : 0.f;
  }
}

// ---------------- device helpers ----------------

// packed fp16 pair, RTZ, one instruction (dst.lo = a, dst.hi = b)
__device__ __forceinline__ unsigned pkrtz(float a, float b) {
  unsigned r;
  asm("v_cvt_pkrtz_f16_f32 %0, %1, %2" : "=v"(r) : "v"(a), "v"(b));
  return r;
}

__device__ __forceinline__ half8v mkfrag(unsigned a0, unsigned a1,
                                         unsigned b0, unsigned b1) {
  uint4v u = {a0, a1, b0, b1};
  return __builtin_bit_cast(half8v, u);
}

// relu + RTZ-pack the accumulators straight into next-layer B fragments.
__device__ __forceinline__ void epilogue(f32x16 (&acc)[2][2],
    half8v (&f)[2][2][2]) {
#pragma unroll
  for (int mt = 0; mt < 2; ++mt)
#pragma unroll
    for (int nt = 0; nt < 2; ++nt)
#pragma unroll
      for (int s = 0; s < 2; ++s) {
        unsigned h[4];
#pragma unroll
        for (int d = 0; d < 4; ++d) {
          float v0 = fmaxf(acc[mt][nt][8 * s + 2 * d + 0], 0.f);
          float v1 = fmaxf(acc[mt][nt][8 * s + 2 * d + 1], 0.f);
          h[d] = pkrtz(v0, v1);
        }
        f[mt][nt][s] = mkfrag(h[0], h[1], h[2], h[3]);
      }
}

__device__ __forceinline__ void mid_layer(const short* wlds, const float* bt,
    int Lbase, int lane, int b5, half8v (&f)[2][2][2]) {
  f32x16 acc[2][2];
  // ks = 0: C operand = compressed bias fragment from LDS (broadcast read)
#pragma unroll
  for (int mt = 0; mt < 2; ++mt) {
    f32x16 bf = *(const f32x16*)(bt + (mt * 2 + b5) * 16);
    half8v a0 = *(const half8v*)(wlds + (Lbase + mt * 4) * 512 + lane * 8);
#pragma unroll
    for (int nt = 0; nt < 2; ++nt)
      acc[mt][nt] = __builtin_amdgcn_mfma_f32_32x32x16_f16(a0, f[0][nt][0], bf, 0, 0, 0);
  }
#pragma unroll
  for (int ks = 1; ks < 4; ++ks) {
#pragma unroll
    for (int mt = 0; mt < 2; ++mt) {
      half8v a = *(const half8v*)(wlds + (Lbase + mt * 4 + ks) * 512 + lane * 8);
      acc[mt][0] = __builtin_amdgcn_mfma_f32_32x32x16_f16(a, f[ks >> 1][0][ks & 1], acc[mt][0], 0, 0, 0);
      acc[mt][1] = __builtin_amdgcn_mfma_f32_32x32x16_f16(a, f[ks >> 1][1][ks & 1], acc[mt][1], 0, 0, 0);
    }
  }
  epilogue(acc, f);
}

__device__ __forceinline__ float ftanh(float x) {
  float e = __expf(2.0f * x);
  return 1.0f - __fdividef(2.0f, e + 1.0f);
}

__global__ __launch_bounds__(512, 8) void fused_kernel(
    const float* __restrict__ x, const short* __restrict__ ws,
    float* __restrict__ out) {
  __shared__ __align__(16) short wlds[16384];  // 32KB mid-layer weight frags
  __shared__ __align__(16) short wl16[3072];   // 6KB L1(2)+L6(4) frags
  __shared__ __align__(64) float blds[352];    // compressed bias tables
  {
    int tid = threadIdx.x;
    const uint4v* src = (const uint4v*)ws;
    // frags 0..5 (L1+L6): 6 frags * 64 uint4v = 384 writes
    if (tid < 384) ((uint4v*)wl16)[tid] = src[tid];
    // frags 6..37 (mid): 32 frags * 64 uint4v = 2048 writes, src from 384
    uint4v* dstM = (uint4v*)wlds;
#pragma unroll
    for (int it = 0; it < 4; ++it)
      dstM[it * 512 + tid] = src[384 + it * 512 + tid];
    const float* wsF = (const float*)ws;
    if (tid < 352) blds[tid] = wsF[BT_BASE + tid];
  }
  __syncthreads();

  const int lane = threadIdx.x & 63;
  const int wave = threadIdx.x >> 6;
  const int b5 = lane >> 5, lo5 = lane & 31;
  const int wavebase = blockIdx.x * 512 + wave * 64;

  half8v f[2][2][2];   // activation B fragments [ms][nt][s]

  // ---------------- layer 1 (K=4 padded, via MFMA) ----------------
  {
    int p = wavebase + lane;
    int pc = p < NPIX ? p : NPIX - 1;
    unsigned jj = (unsigned)pc % 190u;
    unsigned r  = (unsigned)pc / 190u;
    unsigned ii = r % 190u, nn = r / 190u;
    const float* xp = x + ((nn * 192u + ii) * 192u + jj);
    float t0 = xp[0], t1 = xp[1], t2 = xp[192], t3 = xp[193];
    unsigned th0 = pkrtz(t0, t1), th1 = pkrtz(t2, t3);
    // B for tile nt: own-half lanes carry taps in slots j=0..3, other half 0.
    unsigned z = 0u;
    unsigned s0h0 = (b5 == 0) ? th0 : z, s0h1 = (b5 == 0) ? th1 : z;
    unsigned s1h0 = (b5 == 1) ? th0 : z, s1h1 = (b5 == 1) ? th1 : z;
    half8v B0 = mkfrag(s0h0, s0h1, s0h0, s0h1);
    half8v B1 = mkfrag(s1h0, s1h1, s1h0, s1h1);
    f32x16 acc[2][2];
#pragma unroll
    for (int mt = 0; mt < 2; ++mt) {
      f32x16 bf = *(const f32x16*)(blds + 256 + (mt * 2 + b5) * 16);
      half8v a = *(const half8v*)(wl16 + (FR_L1 + mt) * 512 + lane * 8);
      acc[mt][0] = __builtin_amdgcn_mfma_f32_32x32x16_f16(a, B0, bf, 0, 0, 0);
      acc[mt][1] = __builtin_amdgcn_mfma_f32_32x32x16_f16(a, B1, bf, 0, 0, 0);
    }
    epilogue(acc, f);
  }

  // ---------------- layers 2..5 ----------------
  mid_layer(wlds, blds + 0 * 64,  0,  lane, b5, f);
  mid_layer(wlds, blds + 1 * 64,  8,  lane, b5, f);
  mid_layer(wlds, blds + 2 * 64,  16, lane, b5, f);
  mid_layer(wlds, blds + 3 * 64,  24, lane, b5, f);

  // ---------------- layer 6 (M=16 padded) + tanh + shuffle-store ----------------
  {
    f32x16 c6 = *(const f32x16*)(blds + 320 + b5 * 16);
    f32x16 a6[2];
    {
      half8v a = *(const half8v*)(wl16 + (FR_L6 + 0) * 512 + lane * 8);
#pragma unroll
      for (int nt = 0; nt < 2; ++nt)
        a6[nt] = __builtin_amdgcn_mfma_f32_32x32x16_f16(a, f[0][nt][0], c6, 0, 0, 0);
    }
#pragma unroll
    for (int ks = 1; ks < 4; ++ks) {
      half8v a = *(const half8v*)(wl16 + (FR_L6 + ks) * 512 + lane * 8);
      a6[0] = __builtin_amdgcn_mfma_f32_32x32x16_f16(a, f[ks >> 1][0][ks & 1], a6[0], 0, 0, 0);
      a6[1] = __builtin_amdgcn_mfma_f32_32x32x16_f16(a, f[ks >> 1][1][ks & 1], a6[1], 0, 0, 0);
    }
#pragma unroll
    for (int nt = 0; nt < 2; ++nt) {
      int p2 = wavebase + nt * 32 + lo5;
      if (p2 < NPIX) {
        unsigned jj = (unsigned)p2 % 190u;
        unsigned r  = (unsigned)p2 / 190u;
        unsigned ii = r % 190u, nn = r / 190u;
        int base = (int)((nn * 760u + ii * 4u) * 760u + jj * 4u);
        float4 s0, s1;
        s0.x = ftanh(a6[nt][0]); s0.y = ftanh(a6[nt][1]);
        s0.z = ftanh(a6[nt][2]); s0.w = ftanh(a6[nt][3]);
        s1.x = ftanh(a6[nt][4]); s1.y = ftanh(a6[nt][5]);
        s1.z = ftanh(a6[nt][6]); s1.w = ftanh(a6[nt][7]);
        *reinterpret_cast<float4*>(out + base + b5 * 760) = s0;        // rows 0..3: di=b5
        *reinterpret_cast<float4*>(out + base + (2 + b5) * 760) = s1;  // rows 8..11: di=2+b5
      }
    }
  }
}

extern "C" void kernel_launch(void* const* d_in, const int* in_sizes, int n_in,
                              void* d_out, int out_size, void* d_ws, size_t ws_size,
                              hipStream_t stream) {
  const float* x  = (const float*)d_in[0];
  const float* W1 = (const float*)d_in[1];
  const float* b1 = (const float*)d_in[2];
  const float* W2 = (const float*)d_in[3];
  const float* b2 = (const float*)d_in[4];
  const float* W3 = (const float*)d_in[5];
  const float* b3 = (const float*)d_in[6];
  const float* W4 = (const float*)d_in[7];
  const float* b4 = (const float*)d_in[8];
  const float* W5 = (const float*)d_in[9];
  const float* b5 = (const float*)d_in[10];
  const float* W6 = (const float*)d_in[11];
  const float* b6 = (const float*)d_in[12];

  hipLaunchKernelGGL(prep_kernel, dim3(64), dim3(256), 0, stream,
                     W1, W2, W3, W4, W5, W6, b1, b2, b3, b4, b5, b6, (short*)d_ws);
  hipLaunchKernelGGL(fused_kernel, dim3(NWG), dim3(512), 0, stream,
                     x, (const short*)d_ws, (float*)d_out);
}

// Round 16
// 52.337 us; speedup vs baseline: 13.3581x; 13.3581x over previous
//
#include <hip/hip_runtime.h>
#include <cmath>

// SDYUnit: per-pixel conv chain via 32x32x16 fp16 MFMA.
// R16 = R13's PROVEN kernel logic (in-place f epilogue, acc[2][2] ks-major
// mid-layer, separate wlds/wl16/blds LDS buffers, compressed bias tables)
// at R11's PROVEN geometry (256-thread WG, __launch_bounds__(256,4)).
// Only the three staging loops are re-derived for 256 threads.
// Single fp16 weights (RNE) + fp16 activations (RTZ): 76 MFMA/wave.
// Weight k-columns pre-permuted so packed accumulators ARE the next layer's
// B operand: B-slot (h,j) of K-step ks <-> k' = (j&3) + 8*(2ks+(j>>2)) + 4h.

static constexpr int Hh = 190, Ww = 190, Him = 192, Wim = 192, Nimg = 24;
static constexpr int NPIX = Nimg * Hh * Ww;       // 866,400
static constexpr int NWG  = (NPIX + 255) / 256;   // 3385

typedef __attribute__((ext_vector_type(8)))  _Float16 half8v;  // 8 fp16 (4 VGPR)
typedef __attribute__((ext_vector_type(16))) float f32x16;     // C/D frag
typedef __attribute__((ext_vector_type(4)))  unsigned int uint4v;

// fragment indices in ws (each frag = 512 shorts = 1024 B = 64 uint4v)
static constexpr int FR_L1  = 0;    // +mt  (2 frags)
static constexpr int FR_L6  = 2;    // +ks  (4 frags)
static constexpr int FR_MID = 6;    // +(L*8 + mt*4 + ks)  (32 frags)
// compressed bias tables (floats; after 38 frags = 19456 shorts = 9728 f32)
static constexpr int BT_BASE = 9728;  // [0,256) mid [L][mt][b5][16]
                                      // [256,320) L1 [mt][b5][16]
                                      // [320,352) L6 [b5][16]

__global__ __launch_bounds__(256) void prep_kernel(
    const float* __restrict__ W1, const float* __restrict__ W2,
    const float* __restrict__ W3, const float* __restrict__ W4,
    const float* __restrict__ W5, const float* __restrict__ W6,
    const float* __restrict__ b1, const float* __restrict__ b2,
    const float* __restrict__ b3, const float* __restrict__ b4,
    const float* __restrict__ b5, const float* __restrict__ b6,
    short* __restrict__ ws) {
  float* wsF = (float*)ws;
  int t0 = blockIdx.x * 256 + threadIdx.x;
  int stride = gridDim.x * 256;
  // mid layers: A[row][k'], row = mt*32+(lane&31), k' per permuted slot map
  for (int idx = t0; idx < 32 * 512; idx += stride) {
    int j = idx & 7, lane = (idx >> 3) & 63, fi = idx >> 9;
    int ks = fi & 3, mt = (fi >> 2) & 1, L = fi >> 3;
    const float* W = (L == 0) ? W2 : (L == 1) ? W3 : (L == 2) ? W4 : W5;
    int g = mt * 32 + (lane & 31);
    int k = (j & 3) + 8 * (2 * ks + (j >> 2)) + 4 * (lane >> 5);
    _Float16 h = (_Float16)W[g * 64 + k];
    ws[(FR_MID + fi) * 512 + (idx & 511)] = __builtin_bit_cast(short, h);
  }
  // layer 1: taps in slots j=0..3 of BOTH halves (B zeroes the non-owner half)
  for (int idx = t0; idx < 2 * 512; idx += stride) {
    int j = idx & 7, lane = (idx >> 3) & 63, mt = idx >> 9;
    int g = mt * 32 + (lane & 31);
    float w = (j < 4) ? W1[g * 4 + j] : 0.f;
    _Float16 h = (_Float16)w;
    ws[(FR_L1 + mt) * 512 + (idx & 511)] = __builtin_bit_cast(short, h);
  }
  // layer 6: M=16 zero-padded to 32, same permuted k map
  for (int idx = t0; idx < 4 * 512; idx += stride) {
    int j = idx & 7, lane = (idx >> 3) & 63, ks = idx >> 9;
    int g = lane & 31;
    int k = (j & 3) + 8 * (2 * ks + (j >> 2)) + 4 * (lane >> 5);
    float w = (g < 16) ? W6[g * 64 + k] : 0.f;
    _Float16 h = (_Float16)w;
    ws[(FR_L6 + ks) * 512 + (idx & 511)] = __builtin_bit_cast(short, h);
  }
  // compressed bias tables: C/D reg r of lane-half b5 = row (r>>2)*8+b5*4+(r&3)
  for (int idx = t0; idx < 256; idx += stride) {   // mid [L][mt][b5][16]
    int r = idx & 15, b5v = (idx >> 4) & 1, mt = (idx >> 5) & 1, L = idx >> 6;
    const float* bb = (L == 0) ? b2 : (L == 1) ? b3 : (L == 2) ? b4 : b5;
    wsF[BT_BASE + idx] = bb[mt * 32 + (r >> 2) * 8 + b5v * 4 + (r & 3)];
  }
  for (int idx = t0; idx < 64; idx += stride) {    // L1 [mt][b5][16]
    int r = idx & 15, b5v = (idx >> 4) & 1, mt = idx >> 5;
    wsF[BT_BASE + 256 + idx] = b1[mt * 32 + (r >> 2) * 8 + b5v * 4 + (r & 3)];
  }
  for (int idx = t0; idx < 32; idx += stride) {    // L6 [b5][16] (rows>=8 zero)
    int r = idx & 15, b5v = idx >> 4;
    wsF[BT_BASE + 320 + idx] = (r < 8) ? b6[(r >> 2) * 8 + b5v * 4 + (r & 3)] : 0.f;
  }
}

// ---------------- device helpers ----------------

// packed fp16 pair, RTZ, one instruction (dst.lo = a, dst.hi = b)
__device__ __forceinline__ unsigned pkrtz(float a, float b) {
  unsigned r;
  asm("v_cvt_pkrtz_f16_f32 %0, %1, %2" : "=v"(r) : "v"(a), "v"(b));
  return r;
}

__device__ __forceinline__ half8v mkfrag(unsigned a0, unsigned a1,
                                         unsigned b0, unsigned b1) {
  uint4v u = {a0, a1, b0, b1};
  return __builtin_bit_cast(half8v, u);
}

// relu + RTZ-pack the accumulators straight into next-layer B fragments.
__device__ __forceinline__ void epilogue(f32x16 (&acc)[2][2],
    half8v (&f)[2][2][2]) {
#pragma unroll
  for (int mt = 0; mt < 2; ++mt)
#pragma unroll
    for (int nt = 0; nt < 2; ++nt)
#pragma unroll
      for (int s = 0; s < 2; ++s) {
        unsigned h[4];
#pragma unroll
        for (int d = 0; d < 4; ++d) {
          float v0 = fmaxf(acc[mt][nt][8 * s + 2 * d + 0], 0.f);
          float v1 = fmaxf(acc[mt][nt][8 * s + 2 * d + 1], 0.f);
          h[d] = pkrtz(v0, v1);
        }
        f[mt][nt][s] = mkfrag(h[0], h[1], h[2], h[3]);
      }
}

__device__ __forceinline__ void mid_layer(const short* wlds, const float* bt,
    int Lbase, int lane, int b5, half8v (&f)[2][2][2]) {
  f32x16 acc[2][2];
  // ks = 0: C operand = compressed bias fragment from LDS (broadcast read)
#pragma unroll
  for (int mt = 0; mt < 2; ++mt) {
    f32x16 bf = *(const f32x16*)(bt + (mt * 2 + b5) * 16);
    half8v a0 = *(const half8v*)(wlds + (Lbase + mt * 4) * 512 + lane * 8);
#pragma unroll
    for (int nt = 0; nt < 2; ++nt)
      acc[mt][nt] = __builtin_amdgcn_mfma_f32_32x32x16_f16(a0, f[0][nt][0], bf, 0, 0, 0);
  }
#pragma unroll
  for (int ks = 1; ks < 4; ++ks) {
#pragma unroll
    for (int mt = 0; mt < 2; ++mt) {
      half8v a = *(const half8v*)(wlds + (Lbase + mt * 4 + ks) * 512 + lane * 8);
      acc[mt][0] = __builtin_amdgcn_mfma_f32_32x32x16_f16(a, f[ks >> 1][0][ks & 1], acc[mt][0], 0, 0, 0);
      acc[mt][1] = __builtin_amdgcn_mfma_f32_32x32x16_f16(a, f[ks >> 1][1][ks & 1], acc[mt][1], 0, 0, 0);
    }
  }
  epilogue(acc, f);
}

__device__ __forceinline__ float ftanh(float x) {
  float e = __expf(2.0f * x);
  return 1.0f - __fdividef(2.0f, e + 1.0f);
}

__global__ __launch_bounds__(256, 4) void fused_kernel(
    const float* __restrict__ x, const short* __restrict__ ws,
    float* __restrict__ out) {
  __shared__ __align__(16) short wlds[16384];  // 32KB mid-layer weight frags
  __shared__ __align__(16) short wl16[3072];   // 6KB L1(2)+L6(4) frags
  __shared__ __align__(64) float blds[352];    // compressed bias tables
  {
    int tid = threadIdx.x;
    const uint4v* src = (const uint4v*)ws;
    // frags 0..5 (L1+L6): 384 uint4v over 256 threads
    uint4v* dstS = (uint4v*)wl16;
#pragma unroll
    for (int it = 0; it < 2; ++it) {
      int idx = it * 256 + tid;
      if (idx < 384) dstS[idx] = src[idx];
    }
    // frags 6..37 (mid): 2048 uint4v, src from 384
    uint4v* dstM = (uint4v*)wlds;
#pragma unroll
    for (int it = 0; it < 8; ++it)
      dstM[it * 256 + tid] = src[384 + it * 256 + tid];
    const float* wsF = (const float*)ws;
#pragma unroll
    for (int it = 0; it < 2; ++it) {
      int idx = it * 256 + tid;
      if (idx < 352) blds[idx] = wsF[BT_BASE + idx];
    }
  }
  __syncthreads();

  const int lane = threadIdx.x & 63;
  const int wave = threadIdx.x >> 6;
  const int b5 = lane >> 5, lo5 = lane & 31;
  const int wavebase = blockIdx.x * 256 + wave * 64;

  half8v f[2][2][2];   // activation B fragments [ms][nt][s]

  // ---------------- layer 1 (K=4 padded, via MFMA) ----------------
  {
    int p = wavebase + lane;
    int pc = p < NPIX ? p : NPIX - 1;
    unsigned jj = (unsigned)pc % 190u;
    unsigned r  = (unsigned)pc / 190u;
    unsigned ii = r % 190u, nn = r / 190u;
    const float* xp = x + ((nn * 192u + ii) * 192u + jj);
    float t0 = xp[0], t1 = xp[1], t2 = xp[192], t3 = xp[193];
    unsigned th0 = pkrtz(t0, t1), th1 = pkrtz(t2, t3);
    // B for tile nt: own-half lanes carry taps in slots j=0..3, other half 0.
    unsigned z = 0u;
    unsigned s0h0 = (b5 == 0) ? th0 : z, s0h1 = (b5 == 0) ? th1 : z;
    unsigned s1h0 = (b5 == 1) ? th0 : z, s1h1 = (b5 == 1) ? th1 : z;
    half8v B0 = mkfrag(s0h0, s0h1, s0h0, s0h1);
    half8v B1 = mkfrag(s1h0, s1h1, s1h0, s1h1);
    f32x16 acc[2][2];
#pragma unroll
    for (int mt = 0; mt < 2; ++mt) {
      f32x16 bf = *(const f32x16*)(blds + 256 + (mt * 2 + b5) * 16);
      half8v a = *(const half8v*)(wl16 + (FR_L1 + mt) * 512 + lane * 8);
      acc[mt][0] = __builtin_amdgcn_mfma_f32_32x32x16_f16(a, B0, bf, 0, 0, 0);
      acc[mt][1] = __builtin_amdgcn_mfma_f32_32x32x16_f16(a, B1, bf, 0, 0, 0);
    }
    epilogue(acc, f);
  }

  // ---------------- layers 2..5 ----------------
  mid_layer(wlds, blds + 0 * 64,  0,  lane, b5, f);
  mid_layer(wlds, blds + 1 * 64,  8,  lane, b5, f);
  mid_layer(wlds, blds + 2 * 64,  16, lane, b5, f);
  mid_layer(wlds, blds + 3 * 64,  24, lane, b5, f);

  // ---------------- layer 6 (M=16 padded) + tanh + shuffle-store ----------------
  {
    f32x16 c6 = *(const f32x16*)(blds + 320 + b5 * 16);
    f32x16 a6[2];
    {
      half8v a = *(const half8v*)(wl16 + (FR_L6 + 0) * 512 + lane * 8);
#pragma unroll
      for (int nt = 0; nt < 2; ++nt)
        a6[nt] = __builtin_amdgcn_mfma_f32_32x32x16_f16(a, f[0][nt][0], c6, 0, 0, 0);
    }
#pragma unroll
    for (int ks = 1; ks < 4; ++ks) {
      half8v a = *(const half8v*)(wl16 + (FR_L6 + ks) * 512 + lane * 8);
      a6[0] = __builtin_amdgcn_mfma_f32_32x32x16_f16(a, f[ks >> 1][0][ks & 1], a6[0], 0, 0, 0);
      a6[1] = __builtin_amdgcn_mfma_f32_32x32x16_f16(a, f[ks >> 1][1][ks & 1], a6[1], 0, 0, 0);
    }
#pragma unroll
    for (int nt = 0; nt < 2; ++nt) {
      int p2 = wavebase + nt * 32 + lo5;
      if (p2 < NPIX) {
        unsigned jj = (unsigned)p2 % 190u;
        unsigned r  = (unsigned)p2 / 190u;
        unsigned ii = r % 190u, nn = r / 190u;
        int base = (int)((nn * 760u + ii * 4u) * 760u + jj * 4u);
        float4 s0, s1;
        s0.x = ftanh(a6[nt][0]); s0.y = ftanh(a6[nt][1]);
        s0.z = ftanh(a6[nt][2]); s0.w = ftanh(a6[nt][3]);
        s1.x = ftanh(a6[nt][4]); s1.y = ftanh(a6[nt][5]);
        s1.z = ftanh(a6[nt][6]); s1.w = ftanh(a6[nt][7]);
        *reinterpret_cast<float4*>(out + base + b5 * 760) = s0;        // rows 0..3: di=b5
        *reinterpret_cast<float4*>(out + base + (2 + b5) * 760) = s1;  // rows 8..11: di=2+b5
      }
    }
  }
}

extern "C" void kernel_launch(void* const* d_in, const int* in_sizes, int n_in,
                              void* d_out, int out_size, void* d_ws, size_t ws_size,
                              hipStream_t stream) {
  const float* x  = (const float*)d_in[0];
  const float* W1 = (const float*)d_in[1];
  const float* b1 = (const float*)d_in[2];
  const float* W2 = (const float*)d_in[3];
  const float* b2 = (const float*)d_in[4];
  const float* W3 = (const float*)d_in[5];
  const float* b3 = (const float*)d_in[6];
  const float* W4 = (const float*)d_in[7];
  const float* b4 = (const float*)d_in[8];
  const float* W5 = (const float*)d_in[9];
  const float* b5 = (const float*)d_in[10];
  const float* W6 = (const float*)d_in[11];
  const float* b6 = (const float*)d_in[12];

  hipLaunchKernelGGL(prep_kernel, dim3(64), dim3(256), 0, stream,
                     W1, W2, W3, W4, W5, W6, b1, b2, b3, b4, b5, b6, (short*)d_ws);
  hipLaunchKernelGGL(fused_kernel, dim3(NWG), dim3(256), 0, stream,
                     x, (const short*)d_ws, (float*)d_out);
}

// Round 17
// 50.933 us; speedup vs baseline: 13.7262x; 1.0276x over previous
//
#include <hip/hip_runtime.h>
#include <cmath>

// SDYUnit: per-pixel conv chain via 32x32x16 fp16 MFMA.
// R17 = R13's proven-correct 512-thread kernel with ONE change:
// __launch_bounds__(512,4) instead of (512,8). R13's (512,8) forced a
// 64-reg unified cap -> 32-VGPR alloc + 2.4GB scratch spill (699us).
// The body needs 56 VGPR (proven by R16 at a 128-reg cap), and 56 <= 64
// means HW can schedule 8 waves/SIMD: LDS 40448B x 4 WG = 161.8KB fits,
// 4 WG x 512 thr = 2048 = thread cap -> up to 32 waves/CU.
// Single fp16 weights (RNE) + fp16 activations (RTZ): 76 MFMA/wave.
// Weight k-columns pre-permuted so packed accumulators ARE the next layer's
// B operand: B-slot (h,j) of K-step ks <-> k' = (j&3) + 8*(2ks+(j>>2)) + 4h.

static constexpr int Hh = 190, Ww = 190, Him = 192, Wim = 192, Nimg = 24;
static constexpr int NPIX = Nimg * Hh * Ww;       // 866,400
static constexpr int NWG  = (NPIX + 511) / 512;   // 1693

typedef __attribute__((ext_vector_type(8)))  _Float16 half8v;  // 8 fp16 (4 VGPR)
typedef __attribute__((ext_vector_type(16))) float f32x16;     // C/D frag
typedef __attribute__((ext_vector_type(4)))  unsigned int uint4v;

// fragment indices in ws (each frag = 512 shorts = 1024 B = 64 uint4v)
static constexpr int FR_L1  = 0;    // +mt  (2 frags)
static constexpr int FR_L6  = 2;    // +ks  (4 frags)
static constexpr int FR_MID = 6;    // +(L*8 + mt*4 + ks)  (32 frags)
// compressed bias tables (floats; after 38 frags = 19456 shorts = 9728 f32)
static constexpr int BT_BASE = 9728;  // [0,256) mid [L][mt][b5][16]
                                      // [256,320) L1 [mt][b5][16]
                                      // [320,352) L6 [b5][16]

__global__ __launch_bounds__(256) void prep_kernel(
    const float* __restrict__ W1, const float* __restrict__ W2,
    const float* __restrict__ W3, const float* __restrict__ W4,
    const float* __restrict__ W5, const float* __restrict__ W6,
    const float* __restrict__ b1, const float* __restrict__ b2,
    const float* __restrict__ b3, const float* __restrict__ b4,
    const float* __restrict__ b5, const float* __restrict__ b6,
    short* __restrict__ ws) {
  float* wsF = (float*)ws;
  int t0 = blockIdx.x * 256 + threadIdx.x;
  int stride = gridDim.x * 256;
  // mid layers: A[row][k'], row = mt*32+(lane&31), k' per permuted slot map
  for (int idx = t0; idx < 32 * 512; idx += stride) {
    int j = idx & 7, lane = (idx >> 3) & 63, fi = idx >> 9;
    int ks = fi & 3, mt = (fi >> 2) & 1, L = fi >> 3;
    const float* W = (L == 0) ? W2 : (L == 1) ? W3 : (L == 2) ? W4 : W5;
    int g = mt * 32 + (lane & 31);
    int k = (j & 3) + 8 * (2 * ks + (j >> 2)) + 4 * (lane >> 5);
    _Float16 h = (_Float16)W[g * 64 + k];
    ws[(FR_MID + fi) * 512 + (idx & 511)] = __builtin_bit_cast(short, h);
  }
  // layer 1: taps in slots j=0..3 of BOTH halves (B zeroes the non-owner half)
  for (int idx = t0; idx < 2 * 512; idx += stride) {
    int j = idx & 7, lane = (idx >> 3) & 63, mt = idx >> 9;
    int g = mt * 32 + (lane & 31);
    float w = (j < 4) ? W1[g * 4 + j] : 0.f;
    _Float16 h = (_Float16)w;
    ws[(FR_L1 + mt) * 512 + (idx & 511)] = __builtin_bit_cast(short, h);
  }
  // layer 6: M=16 zero-padded to 32, same permuted k map
  for (int idx = t0; idx < 4 * 512; idx += stride) {
    int j = idx & 7, lane = (idx >> 3) & 63, ks = idx >> 9;
    int g = lane & 31;
    int k = (j & 3) + 8 * (2 * ks + (j >> 2)) + 4 * (lane >> 5);
    float w = (g < 16) ? W6[g * 64 + k] : 0.f;
    _Float16 h = (_Float16)w;
    ws[(FR_L6 + ks) * 512 + (idx & 511)] = __builtin_bit_cast(short, h);
  }
  // compressed bias tables: C/D reg r of lane-half b5 = row (r>>2)*8+b5*4+(r&3)
  for (int idx = t0; idx < 256; idx += stride) {   // mid [L][mt][b5][16]
    int r = idx & 15, b5v = (idx >> 4) & 1, mt = (idx >> 5) & 1, L = idx >> 6;
    const float* bb = (L == 0) ? b2 : (L == 1) ? b3 : (L == 2) ? b4 : b5;
    wsF[BT_BASE + idx] = bb[mt * 32 + (r >> 2) * 8 + b5v * 4 + (r & 3)];
  }
  for (int idx = t0; idx < 64; idx += stride) {    // L1 [mt][b5][16]
    int r = idx & 15, b5v = (idx >> 4) & 1, mt = idx >> 5;
    wsF[BT_BASE + 256 + idx] = b1[mt * 32 + (r >> 2) * 8 + b5v * 4 + (r & 3)];
  }
  for (int idx = t0; idx < 32; idx += stride) {    // L6 [b5][16] (rows>=8 zero)
    int r = idx & 15, b5v = idx >> 4;
    wsF[BT_BASE + 320 + idx] = (r < 8) ? b6[(r >> 2) * 8 + b5v * 4 + (r & 3)] : 0.f;
  }
}

// ---------------- device helpers ----------------

// packed fp16 pair, RTZ, one instruction (dst.lo = a, dst.hi = b)
__device__ __forceinline__ unsigned pkrtz(float a, float b) {
  unsigned r;
  asm("v_cvt_pkrtz_f16_f32 %0, %1, %2" : "=v"(r) : "v"(a), "v"(b));
  return r;
}

__device__ __forceinline__ half8v mkfrag(unsigned a0, unsigned a1,
                                         unsigned b0, unsigned b1) {
  uint4v u = {a0, a1, b0, b1};
  return __builtin_bit_cast(half8v, u);
}

// relu + RTZ-pack the accumulators straight into next-layer B fragments.
__device__ __forceinline__ void epilogue(f32x16 (&acc)[2][2],
    half8v (&f)[2][2][2]) {
#pragma unroll
  for (int mt = 0; mt < 2; ++mt)
#pragma unroll
    for (int nt = 0; nt < 2; ++nt)
#pragma unroll
      for (int s = 0; s < 2; ++s) {
        unsigned h[4];
#pragma unroll
        for (int d = 0; d < 4; ++d) {
          float v0 = fmaxf(acc[mt][nt][8 * s + 2 * d + 0], 0.f);
          float v1 = fmaxf(acc[mt][nt][8 * s + 2 * d + 1], 0.f);
          h[d] = pkrtz(v0, v1);
        }
        f[mt][nt][s] = mkfrag(h[0], h[1], h[2], h[3]);
      }
}

__device__ __forceinline__ void mid_layer(const short* wlds, const float* bt,
    int Lbase, int lane, int b5, half8v (&f)[2][2][2]) {
  f32x16 acc[2][2];
  // ks = 0: C operand = compressed bias fragment from LDS (broadcast read)
#pragma unroll
  for (int mt = 0; mt < 2; ++mt) {
    f32x16 bf = *(const f32x16*)(bt + (mt * 2 + b5) * 16);
    half8v a0 = *(const half8v*)(wlds + (Lbase + mt * 4) * 512 + lane * 8);
#pragma unroll
    for (int nt = 0; nt < 2; ++nt)
      acc[mt][nt] = __builtin_amdgcn_mfma_f32_32x32x16_f16(a0, f[0][nt][0], bf, 0, 0, 0);
  }
#pragma unroll
  for (int ks = 1; ks < 4; ++ks) {
#pragma unroll
    for (int mt = 0; mt < 2; ++mt) {
      half8v a = *(const half8v*)(wlds + (Lbase + mt * 4 + ks) * 512 + lane * 8);
      acc[mt][0] = __builtin_amdgcn_mfma_f32_32x32x16_f16(a, f[ks >> 1][0][ks & 1], acc[mt][0], 0, 0, 0);
      acc[mt][1] = __builtin_amdgcn_mfma_f32_32x32x16_f16(a, f[ks >> 1][1][ks & 1], acc[mt][1], 0, 0, 0);
    }
  }
  epilogue(acc, f);
}

__device__ __forceinline__ float ftanh(float x) {
  float e = __expf(2.0f * x);
  return 1.0f - __fdividef(2.0f, e + 1.0f);
}

__global__ __launch_bounds__(512, 4) void fused_kernel(
    const float* __restrict__ x, const short* __restrict__ ws,
    float* __restrict__ out) {
  __shared__ __align__(16) short wlds[16384];  // 32KB mid-layer weight frags
  __shared__ __align__(16) short wl16[3072];   // 6KB L1(2)+L6(4) frags
  __shared__ __align__(64) float blds[352];    // compressed bias tables
  {
    int tid = threadIdx.x;
    const uint4v* src = (const uint4v*)ws;
    // frags 0..5 (L1+L6): 6 frags * 64 uint4v = 384 writes
    if (tid < 384) ((uint4v*)wl16)[tid] = src[tid];
    // frags 6..37 (mid): 32 frags * 64 uint4v = 2048 writes, src from 384
    uint4v* dstM = (uint4v*)wlds;
#pragma unroll
    for (int it = 0; it < 4; ++it)
      dstM[it * 512 + tid] = src[384 + it * 512 + tid];
    const float* wsF = (const float*)ws;
    if (tid < 352) blds[tid] = wsF[BT_BASE + tid];
  }
  __syncthreads();

  const int lane = threadIdx.x & 63;
  const int wave = threadIdx.x >> 6;
  const int b5 = lane >> 5, lo5 = lane & 31;
  const int wavebase = blockIdx.x * 512 + wave * 64;

  half8v f[2][2][2];   // activation B fragments [ms][nt][s]

  // ---------------- layer 1 (K=4 padded, via MFMA) ----------------
  {
    int p = wavebase + lane;
    int pc = p < NPIX ? p : NPIX - 1;
    unsigned jj = (unsigned)pc % 190u;
    unsigned r  = (unsigned)pc / 190u;
    unsigned ii = r % 190u, nn = r / 190u;
    const float* xp = x + ((nn * 192u + ii) * 192u + jj);
    float t0 = xp[0], t1 = xp[1], t2 = xp[192], t3 = xp[193];
    unsigned th0 = pkrtz(t0, t1), th1 = pkrtz(t2, t3);
    // B for tile nt: own-half lanes carry taps in slots j=0..3, other half 0.
    unsigned z = 0u;
    unsigned s0h0 = (b5 == 0) ? th0 : z, s0h1 = (b5 == 0) ? th1 : z;
    unsigned s1h0 = (b5 == 1) ? th0 : z, s1h1 = (b5 == 1) ? th1 : z;
    half8v B0 = mkfrag(s0h0, s0h1, s0h0, s0h1);
    half8v B1 = mkfrag(s1h0, s1h1, s1h0, s1h1);
    f32x16 acc[2][2];
#pragma unroll
    for (int mt = 0; mt < 2; ++mt) {
      f32x16 bf = *(const f32x16*)(blds + 256 + (mt * 2 + b5) * 16);
      half8v a = *(const half8v*)(wl16 + (FR_L1 + mt) * 512 + lane * 8);
      acc[mt][0] = __builtin_amdgcn_mfma_f32_32x32x16_f16(a, B0, bf, 0, 0, 0);
      acc[mt][1] = __builtin_amdgcn_mfma_f32_32x32x16_f16(a, B1, bf, 0, 0, 0);
    }
    epilogue(acc, f);
  }

  // ---------------- layers 2..5 ----------------
  mid_layer(wlds, blds + 0 * 64,  0,  lane, b5, f);
  mid_layer(wlds, blds + 1 * 64,  8,  lane, b5, f);
  mid_layer(wlds, blds + 2 * 64,  16, lane, b5, f);
  mid_layer(wlds, blds + 3 * 64,  24, lane, b5, f);

  // ---------------- layer 6 (M=16 padded) + tanh + shuffle-store ----------------
  {
    f32x16 c6 = *(const f32x16*)(blds + 320 + b5 * 16);
    f32x16 a6[2];
    {
      half8v a = *(const half8v*)(wl16 + (FR_L6 + 0) * 512 + lane * 8);
#pragma unroll
      for (int nt = 0; nt < 2; ++nt)
        a6[nt] = __builtin_amdgcn_mfma_f32_32x32x16_f16(a, f[0][nt][0], c6, 0, 0, 0);
    }
#pragma unroll
    for (int ks = 1; ks < 4; ++ks) {
      half8v a = *(const half8v*)(wl16 + (FR_L6 + ks) * 512 + lane * 8);
      a6[0] = __builtin_amdgcn_mfma_f32_32x32x16_f16(a, f[ks >> 1][0][ks & 1], a6[0], 0, 0, 0);
      a6[1] = __builtin_amdgcn_mfma_f32_32x32x16_f16(a, f[ks >> 1][1][ks & 1], a6[1], 0, 0, 0);
    }
#pragma unroll
    for (int nt = 0; nt < 2; ++nt) {
      int p2 = wavebase + nt * 32 + lo5;
      if (p2 < NPIX) {
        unsigned jj = (unsigned)p2 % 190u;
        unsigned r  = (unsigned)p2 / 190u;
        unsigned ii = r % 190u, nn = r / 190u;
        int base = (int)((nn * 760u + ii * 4u) * 760u + jj * 4u);
        float4 s0, s1;
        s0.x = ftanh(a6[nt][0]); s0.y = ftanh(a6[nt][1]);
        s0.z = ftanh(a6[nt][2]); s0.w = ftanh(a6[nt][3]);
        s1.x = ftanh(a6[nt][4]); s1.y = ftanh(a6[nt][5]);
        s1.z = ftanh(a6[nt][6]); s1.w = ftanh(a6[nt][7]);
        *reinterpret_cast<float4*>(out + base + b5 * 760) = s0;        // rows 0..3: di=b5
        *reinterpret_cast<float4*>(out + base + (2 + b5) * 760) = s1;  // rows 8..11: di=2+b5
      }
    }
  }
}

extern "C" void kernel_launch(void* const* d_in, const int* in_sizes, int n_in,
                              void* d_out, int out_size, void* d_ws, size_t ws_size,
                              hipStream_t stream) {
  const float* x  = (const float*)d_in[0];
  const float* W1 = (const float*)d_in[1];
  const float* b1 = (const float*)d_in[2];
  const float* W2 = (const float*)d_in[3];
  const float* b2 = (const float*)d_in[4];
  const float* W3 = (const float*)d_in[5];
  const float* b3 = (const float*)d_in[6];
  const float* W4 = (const float*)d_in[7];
  const float* b4 = (const float*)d_in[8];
  const float* W5 = (const float*)d_in[9];
  const float* b5 = (const float*)d_in[10];
  const float* W6 = (const float*)d_in[11];
  const float* b6 = (const float*)d_in[12];

  hipLaunchKernelGGL(prep_kernel, dim3(64), dim3(256), 0, stream,
                     W1, W2, W3, W4, W5, W6, b1, b2, b3, b4, b5, b6, (short*)d_ws);
  hipLaunchKernelGGL(fused_kernel, dim3(NWG), dim3(512), 0, stream,
                     x, (const short*)d_ws, (float*)d_out);
}

// Round 18
// 50.176 us; speedup vs baseline: 13.9333x; 1.0151x over previous
//
#include <hip/hip_runtime.h>
#include <cmath>

// SDYUnit: per-pixel conv chain via 32x32x16 fp16 MFMA.
// R18 = R17 (proven, 50.9us) + the single-acc restructure from R14, now that
// R14/R15's failure is root-caused: their 256-thread staging used
// `if (tid<352)` so bias[256:352) was never staged (garbage LDS) -- the
// restructure itself was sound. At 512 threads the guard is correct (R17).
//  - mt/nt-sequential mid-layers: peak live acc = 16 regs -> acc stays in
//    VGPRs, eliminating ~500 v_accvgpr movs/wave; ping-pong fA/fB frags.
//  - x-input loads hoisted above the staging barrier.
// Single fp16 weights (RNE) + fp16 activations (RTZ): 76 MFMA/wave.
// Weight k-columns pre-permuted so packed accumulators ARE the next layer's
// B operand: B-slot (h,j) of K-step ks <-> k' = (j&3) + 8*(2ks+(j>>2)) + 4h.

static constexpr int Hh = 190, Ww = 190, Him = 192, Wim = 192, Nimg = 24;
static constexpr int NPIX = Nimg * Hh * Ww;       // 866,400
static constexpr int NWG  = (NPIX + 511) / 512;   // 1693

typedef __attribute__((ext_vector_type(8)))  _Float16 half8v;  // 8 fp16 (4 VGPR)
typedef __attribute__((ext_vector_type(16))) float f32x16;     // C/D frag
typedef __attribute__((ext_vector_type(4)))  unsigned int uint4v;

// fragment indices in ws (each frag = 512 shorts = 1024 B = 64 uint4v)
static constexpr int FR_L1  = 0;    // +mt  (2 frags)
static constexpr int FR_L6  = 2;    // +ks  (4 frags)
static constexpr int FR_MID = 6;    // +(L*8 + mt*4 + ks)  (32 frags)
// compressed bias tables (floats; after 38 frags = 19456 shorts = 9728 f32)
static constexpr int BT_BASE = 9728;  // [0,256) mid [L][mt][b5][16]
                                      // [256,320) L1 [mt][b5][16]
                                      // [320,352) L6 [b5][16]

__global__ __launch_bounds__(256) void prep_kernel(
    const float* __restrict__ W1, const float* __restrict__ W2,
    const float* __restrict__ W3, const float* __restrict__ W4,
    const float* __restrict__ W5, const float* __restrict__ W6,
    const float* __restrict__ b1, const float* __restrict__ b2,
    const float* __restrict__ b3, const float* __restrict__ b4,
    const float* __restrict__ b5, const float* __restrict__ b6,
    short* __restrict__ ws) {
  float* wsF = (float*)ws;
  int t0 = blockIdx.x * 256 + threadIdx.x;
  int stride = gridDim.x * 256;
  // mid layers: A[row][k'], row = mt*32+(lane&31), k' per permuted slot map
  for (int idx = t0; idx < 32 * 512; idx += stride) {
    int j = idx & 7, lane = (idx >> 3) & 63, fi = idx >> 9;
    int ks = fi & 3, mt = (fi >> 2) & 1, L = fi >> 3;
    const float* W = (L == 0) ? W2 : (L == 1) ? W3 : (L == 2) ? W4 : W5;
    int g = mt * 32 + (lane & 31);
    int k = (j & 3) + 8 * (2 * ks + (j >> 2)) + 4 * (lane >> 5);
    _Float16 h = (_Float16)W[g * 64 + k];
    ws[(FR_MID + fi) * 512 + (idx & 511)] = __builtin_bit_cast(short, h);
  }
  // layer 1: taps in slots j=0..3 of BOTH halves (B zeroes the non-owner half)
  for (int idx = t0; idx < 2 * 512; idx += stride) {
    int j = idx & 7, lane = (idx >> 3) & 63, mt = idx >> 9;
    int g = mt * 32 + (lane & 31);
    float w = (j < 4) ? W1[g * 4 + j] : 0.f;
    _Float16 h = (_Float16)w;
    ws[(FR_L1 + mt) * 512 + (idx & 511)] = __builtin_bit_cast(short, h);
  }
  // layer 6: M=16 zero-padded to 32, same permuted k map
  for (int idx = t0; idx < 4 * 512; idx += stride) {
    int j = idx & 7, lane = (idx >> 3) & 63, ks = idx >> 9;
    int g = lane & 31;
    int k = (j & 3) + 8 * (2 * ks + (j >> 2)) + 4 * (lane >> 5);
    float w = (g < 16) ? W6[g * 64 + k] : 0.f;
    _Float16 h = (_Float16)w;
    ws[(FR_L6 + ks) * 512 + (idx & 511)] = __builtin_bit_cast(short, h);
  }
  // compressed bias tables: C/D reg r of lane-half b5 = row (r>>2)*8+b5*4+(r&3)
  for (int idx = t0; idx < 256; idx += stride) {   // mid [L][mt][b5][16]
    int r = idx & 15, b5v = (idx >> 4) & 1, mt = (idx >> 5) & 1, L = idx >> 6;
    const float* bb = (L == 0) ? b2 : (L == 1) ? b3 : (L == 2) ? b4 : b5;
    wsF[BT_BASE + idx] = bb[mt * 32 + (r >> 2) * 8 + b5v * 4 + (r & 3)];
  }
  for (int idx = t0; idx < 64; idx += stride) {    // L1 [mt][b5][16]
    int r = idx & 15, b5v = (idx >> 4) & 1, mt = idx >> 5;
    wsF[BT_BASE + 256 + idx] = b1[mt * 32 + (r >> 2) * 8 + b5v * 4 + (r & 3)];
  }
  for (int idx = t0; idx < 32; idx += stride) {    // L6 [b5][16] (rows>=8 zero)
    int r = idx & 15, b5v = idx >> 4;
    wsF[BT_BASE + 320 + idx] = (r < 8) ? b6[(r >> 2) * 8 + b5v * 4 + (r & 3)] : 0.f;
  }
}

// ---------------- device helpers ----------------

// packed fp16 pair, RTZ, one instruction (dst.lo = a, dst.hi = b)
__device__ __forceinline__ unsigned pkrtz(float a, float b) {
  unsigned r;
  asm("v_cvt_pkrtz_f16_f32 %0, %1, %2" : "=v"(r) : "v"(a), "v"(b));
  return r;
}

__device__ __forceinline__ half8v mkfrag(unsigned a0, unsigned a1,
                                         unsigned b0, unsigned b1) {
  uint4v u = {a0, a1, b0, b1};
  return __builtin_bit_cast(half8v, u);
}

// relu (f32 fmax) + RTZ-pack one 16-value acc tile -> two B-frag halves [s].
__device__ __forceinline__ void epi_tile(const f32x16& acc, half8v (&o)[2]) {
#pragma unroll
  for (int s = 0; s < 2; ++s) {
    unsigned h[4];
#pragma unroll
    for (int d = 0; d < 4; ++d) {
      float v0 = fmaxf(acc[8 * s + 2 * d + 0], 0.f);
      float v1 = fmaxf(acc[8 * s + 2 * d + 1], 0.f);
      h[d] = pkrtz(v0, v1);
    }
    o[s] = mkfrag(h[0], h[1], h[2], h[3]);
  }
}

// one 64->64 layer: mt-sequential, nt-sequential (peak live acc = 16 regs).
// fo = input frags, fn = output frags (must not alias).
__device__ __forceinline__ void mid_layer(const short* wlds, const float* bt,
    int Lbase, int lane, int b5,
    half8v (&fo)[2][2][2], half8v (&fn)[2][2][2]) {
#pragma unroll
  for (int mt = 0; mt < 2; ++mt) {
    const short* wb = wlds + (Lbase + mt * 4) * 512 + lane * 8;
    half8v a0 = *(const half8v*)(wb + 0 * 512);
    half8v a1 = *(const half8v*)(wb + 1 * 512);
    half8v a2 = *(const half8v*)(wb + 2 * 512);
    half8v a3 = *(const half8v*)(wb + 3 * 512);
    f32x16 bf = *(const f32x16*)(bt + (mt * 2 + b5) * 16);
#pragma unroll
    for (int nt = 0; nt < 2; ++nt) {
      f32x16 acc;
      acc = __builtin_amdgcn_mfma_f32_32x32x16_f16(a0, fo[0][nt][0], bf, 0, 0, 0);
      acc = __builtin_amdgcn_mfma_f32_32x32x16_f16(a1, fo[0][nt][1], acc, 0, 0, 0);
      acc = __builtin_amdgcn_mfma_f32_32x32x16_f16(a2, fo[1][nt][0], acc, 0, 0, 0);
      acc = __builtin_amdgcn_mfma_f32_32x32x16_f16(a3, fo[1][nt][1], acc, 0, 0, 0);
      epi_tile(acc, fn[mt][nt]);
    }
  }
}

__device__ __forceinline__ float ftanh(float x) {
  float e = __expf(2.0f * x);
  return 1.0f - __fdividef(2.0f, e + 1.0f);
}

__global__ __launch_bounds__(512, 4) void fused_kernel(
    const float* __restrict__ x, const short* __restrict__ ws,
    float* __restrict__ out) {
  __shared__ __align__(16) short wlds[16384];  // 32KB mid-layer weight frags
  __shared__ __align__(16) short wl16[3072];   // 6KB L1(2)+L6(4) frags
  __shared__ __align__(64) float blds[352];    // compressed bias tables

  const int lane = threadIdx.x & 63;
  const int wave = threadIdx.x >> 6;
  const int b5 = lane >> 5, lo5 = lane & 31;
  const int wavebase = blockIdx.x * 512 + wave * 64;

  // ---- hoisted x loads (HBM latency hides under staging + barrier) ----
  int p = wavebase + lane;
  int pc = p < NPIX ? p : NPIX - 1;
  unsigned jj0 = (unsigned)pc % 190u;
  unsigned r0  = (unsigned)pc / 190u;
  unsigned ii0 = r0 % 190u, nn0 = r0 / 190u;
  const float* xp = x + ((nn0 * 192u + ii0) * 192u + jj0);
  float t0 = xp[0], t1 = xp[1], t2 = xp[192], t3 = xp[193];

  // ---- stage weight frags + bias tables into LDS (R17-proven, 512 thr) ----
  {
    int tid = threadIdx.x;
    const uint4v* src = (const uint4v*)ws;
    // frags 0..5 (L1+L6): 6 frags * 64 uint4v = 384 writes
    if (tid < 384) ((uint4v*)wl16)[tid] = src[tid];
    // frags 6..37 (mid): 32 frags * 64 uint4v = 2048 writes, src from 384
    uint4v* dstM = (uint4v*)wlds;
#pragma unroll
    for (int it = 0; it < 4; ++it)
      dstM[it * 512 + tid] = src[384 + it * 512 + tid];
    const float* wsF = (const float*)ws;
    if (tid < 352) blds[tid] = wsF[BT_BASE + tid];   // valid: 512 threads
  }
  __syncthreads();

  half8v fA[2][2][2], fB[2][2][2];   // ping-pong activation B fragments

  // ---------------- layer 1 (K=4 padded, via MFMA) -> fA ----------------
  {
    unsigned th0 = pkrtz(t0, t1), th1 = pkrtz(t2, t3);
    // B for tile nt: own-half lanes carry taps in slots j=0..3, other half 0.
    unsigned z = 0u;
    unsigned s0h0 = (b5 == 0) ? th0 : z, s0h1 = (b5 == 0) ? th1 : z;
    unsigned s1h0 = (b5 == 1) ? th0 : z, s1h1 = (b5 == 1) ? th1 : z;
    half8v Bv[2];
    Bv[0] = mkfrag(s0h0, s0h1, s0h0, s0h1);
    Bv[1] = mkfrag(s1h0, s1h1, s1h0, s1h1);
#pragma unroll
    for (int mt = 0; mt < 2; ++mt) {
      f32x16 bf = *(const f32x16*)(blds + 256 + (mt * 2 + b5) * 16);
      half8v a = *(const half8v*)(wl16 + (FR_L1 + mt) * 512 + lane * 8);
#pragma unroll
      for (int nt = 0; nt < 2; ++nt) {
        f32x16 acc = __builtin_amdgcn_mfma_f32_32x32x16_f16(a, Bv[nt], bf, 0, 0, 0);
        epi_tile(acc, fA[mt][nt]);
      }
    }
  }

  // ---------------- layers 2..5 (ping-pong fA/fB) ----------------
  mid_layer(wlds, blds + 0 * 64, 0,  lane, b5, fA, fB);
  mid_layer(wlds, blds + 1 * 64, 8,  lane, b5, fB, fA);
  mid_layer(wlds, blds + 2 * 64, 16, lane, b5, fA, fB);
  mid_layer(wlds, blds + 3 * 64, 24, lane, b5, fB, fA);

  // ---------------- layer 6 (M=16 padded) + tanh + shuffle-store ----------------
  {
    f32x16 c6 = *(const f32x16*)(blds + 320 + b5 * 16);
    const short* wb = wl16 + FR_L6 * 512 + lane * 8;
    half8v a0 = *(const half8v*)(wb + 0 * 512);
    half8v a1 = *(const half8v*)(wb + 1 * 512);
    half8v a2 = *(const half8v*)(wb + 2 * 512);
    half8v a3 = *(const half8v*)(wb + 3 * 512);
#pragma unroll
    for (int nt = 0; nt < 2; ++nt) {
      f32x16 a6;
      a6 = __builtin_amdgcn_mfma_f32_32x32x16_f16(a0, fA[0][nt][0], c6, 0, 0, 0);
      a6 = __builtin_amdgcn_mfma_f32_32x32x16_f16(a1, fA[0][nt][1], a6, 0, 0, 0);
      a6 = __builtin_amdgcn_mfma_f32_32x32x16_f16(a2, fA[1][nt][0], a6, 0, 0, 0);
      a6 = __builtin_amdgcn_mfma_f32_32x32x16_f16(a3, fA[1][nt][1], a6, 0, 0, 0);
      int p2 = wavebase + nt * 32 + lo5;
      if (p2 < NPIX) {
        unsigned jj = (unsigned)p2 % 190u;
        unsigned r  = (unsigned)p2 / 190u;
        unsigned ii = r % 190u, nn = r / 190u;
        int base = (int)((nn * 760u + ii * 4u) * 760u + jj * 4u);
        float4 s0, s1;
        s0.x = ftanh(a6[0]); s0.y = ftanh(a6[1]);
        s0.z = ftanh(a6[2]); s0.w = ftanh(a6[3]);
        s1.x = ftanh(a6[4]); s1.y = ftanh(a6[5]);
        s1.z = ftanh(a6[6]); s1.w = ftanh(a6[7]);
        *reinterpret_cast<float4*>(out + base + b5 * 760) = s0;        // rows 0..3: di=b5
        *reinterpret_cast<float4*>(out + base + (2 + b5) * 760) = s1;  // rows 8..11: di=2+b5
      }
    }
  }
}

extern "C" void kernel_launch(void* const* d_in, const int* in_sizes, int n_in,
                              void* d_out, int out_size, void* d_ws, size_t ws_size,
                              hipStream_t stream) {
  const float* x  = (const float*)d_in[0];
  const float* W1 = (const float*)d_in[1];
  const float* b1 = (const float*)d_in[2];
  const float* W2 = (const float*)d_in[3];
  const float* b2 = (const float*)d_in[4];
  const float* W3 = (const float*)d_in[5];
  const float* b3 = (const float*)d_in[6];
  const float* W4 = (const float*)d_in[7];
  const float* b4 = (const float*)d_in[8];
  const float* W5 = (const float*)d_in[9];
  const float* b5 = (const float*)d_in[10];
  const float* W6 = (const float*)d_in[11];
  const float* b6 = (const float*)d_in[12];

  hipLaunchKernelGGL(prep_kernel, dim3(64), dim3(256), 0, stream,
                     W1, W2, W3, W4, W5, W6, b1, b2, b3, b4, b5, b6, (short*)d_ws);
  hipLaunchKernelGGL(fused_kernel, dim3(NWG), dim3(512), 0, stream,
                     x, (const short*)d_ws, (float*)d_out);
}